// Round 1
// baseline (192.294 us; speedup 1.0000x reference)
//
#include <hip/hip_runtime.h>
#include <hip/hip_bf16.h>

typedef __attribute__((ext_vector_type(8))) __bf16 bf16x8;
typedef __attribute__((ext_vector_type(4))) __bf16 bf16x4;
typedef __attribute__((ext_vector_type(2))) __bf16 bf16x2;
typedef __attribute__((ext_vector_type(4))) float  f32x4;

#define MFMA16(a, b, c) __builtin_amdgcn_mfma_f32_16x16x32_bf16((a), (b), (c), 0, 0, 0)

// Problem constants: B=2, S=4096, D=256, P=R=64. Rows flattened g = b*4096 + n (8192 total).
static constexpr size_t OFF_XB  = 0;                         // bf16 [8192][256]  (4 MiB)
static constexpr size_t OFF_WVT = 4u << 20;                  // bf16 [256][256]   ([n][k])
static constexpr size_t OFF_WLT = OFF_WVT + 256 * 256 * 2;   // bf16 [64][256]
static constexpr size_t OFF_WRT = OFF_WLT + 64 * 256 * 2;    // bf16 [64][256]
static constexpr size_t OFF_WOT = OFF_WRT + 64 * 256 * 2;    // bf16 [256][256]
static constexpr size_t OFF_VT  = 5u << 20;                  // bf16 [2][256][4096]  V^T per batch (4 MiB)
static constexpr size_t OFF_L   = 9u << 20;                  // f32  [8192][64]
static constexpr size_t OFF_R   = 11u << 20;                 // f32  [8192][64]
static constexpr size_t OFF_OP  = 13u << 20;                 // bf16 [8192][256]  out_pre

// ---------------------------------------------------------------- x -> bf16
__global__ __launch_bounds__(256) void k_cvt_x(const float* __restrict__ x,
                                               __bf16* __restrict__ xb) {
  const int i = (blockIdx.x * 256 + threadIdx.x) * 4;
  const float4 v = *(const float4*)(x + i);
  bf16x4 o;
  o.x = (__bf16)v.x; o.y = (__bf16)v.y; o.z = (__bf16)v.z; o.w = (__bf16)v.w;
  *(bf16x4*)(xb + i) = o;
}

// ------------------------------------- weights: transpose to [n][k], bf16
__global__ __launch_bounds__(256) void k_prep_w(const float* __restrict__ Wv,
                                                const float* __restrict__ Wl,
                                                const float* __restrict__ Wr,
                                                const float* __restrict__ Wo,
                                                __bf16* __restrict__ Wvt,
                                                __bf16* __restrict__ Wlt,
                                                __bf16* __restrict__ Wrt,
                                                __bf16* __restrict__ Wot) {
  const int idx = blockIdx.x * 256 + threadIdx.x;  // 0 .. 163839
  if (idx < 65536) {                     // Wv (256x256)
    const int k = idx >> 8, n = idx & 255;
    Wvt[n * 256 + k] = (__bf16)Wv[idx];
  } else if (idx < 81920) {              // Wl (256x64)
    const int j = idx - 65536;
    const int k = j >> 6, n = j & 63;
    Wlt[n * 256 + k] = (__bf16)Wl[j];
  } else if (idx < 98304) {              // Wr (256x64)
    const int j = idx - 81920;
    const int k = j >> 6, n = j & 63;
    Wrt[n * 256 + k] = (__bf16)Wr[j];
  } else {                               // Wo (256x256)
    const int j = idx - 98304;
    const int k = j >> 8, n = j & 255;
    Wot[n * 256 + k] = (__bf16)Wo[j];
  }
}

// ------------------- projections: V^T (bf16), l, r (fp32) via MFMA GEMM
// grid (128, 6): blockIdx.x = 64-row block; blockIdx.y: 0..3 -> Wv col tiles, 4 -> Wl, 5 -> Wr
__global__ __launch_bounds__(256) void k_proj(const __bf16* __restrict__ xb,
                                              const __bf16* __restrict__ Wvt,
                                              const __bf16* __restrict__ Wlt,
                                              const __bf16* __restrict__ Wrt,
                                              __bf16* __restrict__ Vt,
                                              float* __restrict__ lbuf,
                                              float* __restrict__ rbuf) {
  const int t = threadIdx.x;
  const int lane = t & 63, wave = t >> 6;
  const int l16 = lane & 15, quad = lane >> 4;
  const int wr = wave >> 1, wc = wave & 1;
  const int rbk = blockIdx.x;
  const int ct  = blockIdx.y;
  const __bf16* Wt;
  int colbase;
  if (ct < 4)       { Wt = Wvt; colbase = ct * 64; }
  else if (ct == 4) { Wt = Wlt; colbase = 0; }
  else              { Wt = Wrt; colbase = 0; }
  const int row0 = rbk * 64 + wr * 32;
  const int c0   = colbase + wc * 32;
  f32x4 acc[2][2] = {};
  for (int kk = 0; kk < 256; kk += 32) {
    const int ko = kk + quad * 8;
    bf16x8 a0 = *(const bf16x8*)(xb + (size_t)(row0 + l16) * 256 + ko);
    bf16x8 a1 = *(const bf16x8*)(xb + (size_t)(row0 + 16 + l16) * 256 + ko);
    bf16x8 b0 = *(const bf16x8*)(Wt + (size_t)(c0 + l16) * 256 + ko);
    bf16x8 b1 = *(const bf16x8*)(Wt + (size_t)(c0 + 16 + l16) * 256 + ko);
    acc[0][0] = MFMA16(a0, b0, acc[0][0]);
    acc[0][1] = MFMA16(a0, b1, acc[0][1]);
    acc[1][0] = MFMA16(a1, b0, acc[1][0]);
    acc[1][1] = MFMA16(a1, b1, acc[1][1]);
  }
#pragma unroll
  for (int mt = 0; mt < 2; ++mt)
#pragma unroll
    for (int nt = 0; nt < 2; ++nt) {
      const int col  = c0 + nt * 16 + l16;
      const int rloc = wr * 32 + mt * 16 + quad * 4;  // D row = quad*4 + reg
      const int gr   = rbk * 64 + rloc;
      if (ct < 4) {
        const int b  = gr >> 12;
        const int n0 = gr & 4095;
        bf16x4 o;
        o.x = (__bf16)acc[mt][nt][0];
        o.y = (__bf16)acc[mt][nt][1];
        o.z = (__bf16)acc[mt][nt][2];
        o.w = (__bf16)acc[mt][nt][3];
        *(bf16x4*)(Vt + (size_t)b * (256 * 4096) + (size_t)col * 4096 + n0) = o;
      } else {
        float* dst = (ct == 4) ? lbuf : rbuf;
#pragma unroll
        for (int rr = 0; rr < 4; ++rr)
          dst[(size_t)(gr + rr) * 64 + col] = acc[mt][nt][rr];
      }
    }
}

// ---------- fused attention GEMM: out_pre = softmax(P) @ V, P generated per K-chunk
// grid (128, 2): 64-row blocks x 128-col tiles. 4 waves in 2x2 (32 rows x 64 cols each).
__global__ __launch_bounds__(256) void k_attn(const float* __restrict__ lbuf,
                                              const float* __restrict__ rbuf,
                                              const __bf16* __restrict__ Vt,
                                              __bf16* __restrict__ op) {
  __shared__ float lt[64 * 65];                 // +1 pad: kills bank conflicts
  __shared__ float rt[64 * 65];
  __shared__ __align__(16) __bf16 pt[64 * 72];  // P tile, stride 72 -> 2-way only
  __shared__ float zred[256];
  __shared__ float invz[64];
  const int t  = threadIdx.x;
  const int rbk = blockIdx.x;
  const int ct  = blockIdx.y;
  const int g0  = rbk * 64;
  const int b   = g0 >> 12;
  for (int i = t; i < 4096; i += 256) {
    const int rr = i >> 6, pp = i & 63;
    lt[rr * 65 + pp] = lbuf[(size_t)(g0 + rr) * 64 + pp];
    rt[rr * 65 + pp] = rbuf[(size_t)(g0 + rr) * 64 + pp];
  }
  const int lane = t & 63, wave = t >> 6;
  const int l16 = lane & 15, quad = lane >> 4;
  const int wr = wave >> 1, wc = wave & 1;
  const int prow = t >> 2;           // P-gen: 4 threads per row
  const int pq0  = (t & 3) * 16;     // each covers 16 q values
  const int colw = ct * 128 + wc * 64;
  const __bf16* Vb = Vt + (size_t)b * (256 * 4096);
  float zacc = 0.f;
  f32x4 acc[2][4] = {};
  for (int kc = 0; kc < 64; ++kc) {
    __syncthreads();  // prev MFMA reads of pt done (also guards lt/rt load at kc=0)
    const float lv = lt[prow * 65 + kc];
#pragma unroll
    for (int i = 0; i < 16; i += 2) {
      const float e0 = __expf(lv * rt[prow * 65 + pq0 + i]);
      const float e1 = __expf(lv * rt[prow * 65 + pq0 + i + 1]);
      zacc += e0;
      zacc += e1;
      bf16x2 pv;
      pv.x = (__bf16)e0;
      pv.y = (__bf16)e1;
      *(bf16x2*)(pt + prow * 72 + pq0 + i) = pv;
    }
    __syncthreads();  // pt ready
#pragma unroll
    for (int kk = 0; kk < 2; ++kk) {
      const int ko = kk * 32 + quad * 8;
      bf16x8 a0 = *(const bf16x8*)(pt + (wr * 32 + l16) * 72 + ko);
      bf16x8 a1 = *(const bf16x8*)(pt + (wr * 32 + 16 + l16) * 72 + ko);
      const int kg = kc * 64 + ko;
#pragma unroll
      for (int nt = 0; nt < 4; ++nt) {
        bf16x8 bv = *(const bf16x8*)(Vb + (size_t)(colw + nt * 16 + l16) * 4096 + kg);
        acc[0][nt] = MFMA16(a0, bv, acc[0][nt]);
        acc[1][nt] = MFMA16(a1, bv, acc[1][nt]);
      }
    }
  }
  zred[t] = zacc;
  __syncthreads();
  if (t < 64)
    invz[t] = 1.0f / (zred[t * 4] + zred[t * 4 + 1] + zred[t * 4 + 2] + zred[t * 4 + 3]);
  __syncthreads();
#pragma unroll
  for (int mt = 0; mt < 2; ++mt)
#pragma unroll
    for (int nt = 0; nt < 4; ++nt) {
      const int col  = colw + nt * 16 + l16;
      const int rloc = wr * 32 + mt * 16 + quad * 4;
#pragma unroll
      for (int rr = 0; rr < 4; ++rr) {
        const float v = acc[mt][nt][rr] * invz[rloc + rr];
        op[(size_t)(g0 + rloc + rr) * 256 + col] = (__bf16)v;
      }
    }
}

// ----------------------------------------- out = out_pre @ Wo (fp32 result)
// grid (128, 4)
__global__ __launch_bounds__(256) void k_out(const __bf16* __restrict__ op,
                                             const __bf16* __restrict__ Wot,
                                             float* __restrict__ out) {
  const int t = threadIdx.x;
  const int lane = t & 63, wave = t >> 6;
  const int l16 = lane & 15, quad = lane >> 4;
  const int wr = wave >> 1, wc = wave & 1;
  const int rbk = blockIdx.x;
  const int ct  = blockIdx.y;
  const int row0 = rbk * 64 + wr * 32;
  const int c0   = ct * 64 + wc * 32;
  f32x4 acc[2][2] = {};
  for (int kk = 0; kk < 256; kk += 32) {
    const int ko = kk + quad * 8;
    bf16x8 a0 = *(const bf16x8*)(op + (size_t)(row0 + l16) * 256 + ko);
    bf16x8 a1 = *(const bf16x8*)(op + (size_t)(row0 + 16 + l16) * 256 + ko);
    bf16x8 b0 = *(const bf16x8*)(Wot + (size_t)(c0 + l16) * 256 + ko);
    bf16x8 b1 = *(const bf16x8*)(Wot + (size_t)(c0 + 16 + l16) * 256 + ko);
    acc[0][0] = MFMA16(a0, b0, acc[0][0]);
    acc[0][1] = MFMA16(a0, b1, acc[0][1]);
    acc[1][0] = MFMA16(a1, b0, acc[1][0]);
    acc[1][1] = MFMA16(a1, b1, acc[1][1]);
  }
#pragma unroll
  for (int mt = 0; mt < 2; ++mt)
#pragma unroll
    for (int nt = 0; nt < 2; ++nt) {
      const int col = c0 + nt * 16 + l16;
      const int r0  = row0 + mt * 16 + quad * 4;
#pragma unroll
      for (int rr = 0; rr < 4; ++rr)
        out[(size_t)(r0 + rr) * 256 + col] = acc[mt][nt][rr];
    }
}

extern "C" void kernel_launch(void* const* d_in, const int* in_sizes, int n_in,
                              void* d_out, int out_size, void* d_ws, size_t ws_size,
                              hipStream_t stream) {
  const float* x  = (const float*)d_in[0];
  const float* Wl = (const float*)d_in[1];
  const float* Wr = (const float*)d_in[2];
  const float* Wv = (const float*)d_in[3];
  const float* Wo = (const float*)d_in[4];
  char* ws = (char*)d_ws;
  __bf16* xb  = (__bf16*)(ws + OFF_XB);
  __bf16* Wvt = (__bf16*)(ws + OFF_WVT);
  __bf16* Wlt = (__bf16*)(ws + OFF_WLT);
  __bf16* Wrt = (__bf16*)(ws + OFF_WRT);
  __bf16* Wot = (__bf16*)(ws + OFF_WOT);
  __bf16* Vt  = (__bf16*)(ws + OFF_VT);
  float*  lb  = (float*)(ws + OFF_L);
  float*  rbf = (float*)(ws + OFF_R);
  __bf16* op  = (__bf16*)(ws + OFF_OP);
  float*  out = (float*)d_out;

  k_cvt_x<<<2048, 256, 0, stream>>>(x, xb);
  k_prep_w<<<640, 256, 0, stream>>>(Wv, Wl, Wr, Wo, Wvt, Wlt, Wrt, Wot);
  k_proj<<<dim3(128, 6), 256, 0, stream>>>(xb, Wvt, Wlt, Wrt, Vt, lb, rbf);
  k_attn<<<dim3(128, 2), 256, 0, stream>>>(lb, rbf, Vt, op);
  k_out<<<dim3(128, 4), 256, 0, stream>>>(op, Wot, out);
}

// Round 2
// 152.153 us; speedup vs baseline: 1.2638x; 1.2638x over previous
//
#include <hip/hip_runtime.h>
#include <hip/hip_bf16.h>

typedef __attribute__((ext_vector_type(8))) __bf16 bf16x8;
typedef __attribute__((ext_vector_type(4))) __bf16 bf16x4;
typedef __attribute__((ext_vector_type(4))) float  f32x4;

#define MFMA16(a, b, c) __builtin_amdgcn_mfma_f32_16x16x32_bf16((a), (b), (c), 0, 0, 0)

// B=2, S=4096, D=256, P=R=64. Flattened rows g = b*4096 + n (8192 total).
static constexpr size_t OFF_XB   = 0;                        // bf16 [8192][256]   4 MiB
static constexpr size_t OFF_WVT  = 4u << 20;                 // bf16 [256][256] ([n][k])
static constexpr size_t OFF_WLT  = OFF_WVT + 256 * 256 * 2;  // bf16 [64][256]
static constexpr size_t OFF_WRT  = OFF_WLT + 64 * 256 * 2;   // bf16 [64][256]
static constexpr size_t OFF_WOT  = OFF_WRT + 64 * 256 * 2;   // bf16 [256][256]
static constexpr size_t OFF_VT   = 5u << 20;                 // bf16 [2][256][4096] V^T  4 MiB
static constexpr size_t OFF_L    = 9u << 20;                 // f32  [8192][64]    2 MiB
static constexpr size_t OFF_R    = 11u << 20;                // f32  [8192][64]    2 MiB
static constexpr size_t OFF_OP   = 13u << 20;                // bf16 [8192][256]   4 MiB
static constexpr size_t OFF_PART = 17u << 20;                // bf16 [8][8192][256] 32 MiB
static constexpr size_t OFF_ZP   = 49u << 20;                // f32  [8][8192]     256 KiB

// ------------------------------------------- x -> bf16  +  weight transpose
__global__ __launch_bounds__(256) void k_prep(const float* __restrict__ x,
                                              const float* __restrict__ Wv,
                                              const float* __restrict__ Wl,
                                              const float* __restrict__ Wr,
                                              const float* __restrict__ Wo,
                                              __bf16* __restrict__ xb,
                                              __bf16* __restrict__ Wvt,
                                              __bf16* __restrict__ Wlt,
                                              __bf16* __restrict__ Wrt,
                                              __bf16* __restrict__ Wot) {
  const int bx = blockIdx.x, t = threadIdx.x;
  if (bx < 2048) {                      // x conversion: 2,097,152 elems / 4
    const int i = (bx * 256 + t) * 4;
    const float4 v = *(const float4*)(x + i);
    bf16x4 o;
    o.x = (__bf16)v.x; o.y = (__bf16)v.y; o.z = (__bf16)v.z; o.w = (__bf16)v.w;
    *(bf16x4*)(xb + i) = o;
    return;
  }
  const int idx = (bx - 2048) * 256 + t;  // 0 .. 163839
  if (idx < 65536) {                      // Wv (256x256)
    const int k = idx >> 8, n = idx & 255;
    Wvt[n * 256 + k] = (__bf16)Wv[idx];
  } else if (idx < 81920) {               // Wl (256x64)
    const int j = idx - 65536;
    const int k = j >> 6, n = j & 63;
    Wlt[n * 256 + k] = (__bf16)Wl[j];
  } else if (idx < 98304) {               // Wr (256x64)
    const int j = idx - 81920;
    const int k = j >> 6, n = j & 63;
    Wrt[n * 256 + k] = (__bf16)Wr[j];
  } else {                                // Wo (256x256)
    const int j = idx - 98304;
    const int k = j >> 8, n = j & 255;
    Wot[n * 256 + k] = (__bf16)Wo[j];
  }
}

// ------------------- projections: V^T (bf16, [col][k], coalesced via LDS), l, r
// grid (128, 6): x = 64-row block; y: 0..3 Wv col tiles, 4 -> Wl, 5 -> Wr
__global__ __launch_bounds__(256) void k_proj(const __bf16* __restrict__ xb,
                                              const __bf16* __restrict__ Wvt,
                                              const __bf16* __restrict__ Wlt,
                                              const __bf16* __restrict__ Wrt,
                                              __bf16* __restrict__ Vt,
                                              float* __restrict__ lbuf,
                                              float* __restrict__ rbuf) {
  __shared__ __align__(16) __bf16 vs[64 * 72];
  const int t = threadIdx.x;
  const int lane = t & 63, wave = t >> 6;
  const int l16 = lane & 15, quad = lane >> 4;
  const int wr = wave >> 1, wc = wave & 1;
  const int rbk = blockIdx.x;
  const int ct  = blockIdx.y;
  const __bf16* Wt;
  int colbase;
  if (ct < 4)       { Wt = Wvt; colbase = ct * 64; }
  else if (ct == 4) { Wt = Wlt; colbase = 0; }
  else              { Wt = Wrt; colbase = 0; }
  const int row0 = rbk * 64 + wr * 32;
  const int c0   = colbase + wc * 32;
  f32x4 acc[2][2] = {};
  for (int kk = 0; kk < 256; kk += 32) {
    const int ko = kk + quad * 8;
    bf16x8 a0 = *(const bf16x8*)(xb + (size_t)(row0 + l16) * 256 + ko);
    bf16x8 a1 = *(const bf16x8*)(xb + (size_t)(row0 + 16 + l16) * 256 + ko);
    bf16x8 b0 = *(const bf16x8*)(Wt + (size_t)(c0 + l16) * 256 + ko);
    bf16x8 b1 = *(const bf16x8*)(Wt + (size_t)(c0 + 16 + l16) * 256 + ko);
    acc[0][0] = MFMA16(a0, b0, acc[0][0]);
    acc[0][1] = MFMA16(a0, b1, acc[0][1]);
    acc[1][0] = MFMA16(a1, b0, acc[1][0]);
    acc[1][1] = MFMA16(a1, b1, acc[1][1]);
  }
  if (ct < 4) {
    // stage tile into LDS [col_local][k_local] (stride 72), then coalesced write
#pragma unroll
    for (int mt = 0; mt < 2; ++mt)
#pragma unroll
      for (int nt = 0; nt < 2; ++nt) {
        const int col_l = wc * 32 + nt * 16 + l16;
        const int k_l   = wr * 32 + mt * 16 + quad * 4;
        bf16x4 o;
        o.x = (__bf16)acc[mt][nt][0];
        o.y = (__bf16)acc[mt][nt][1];
        o.z = (__bf16)acc[mt][nt][2];
        o.w = (__bf16)acc[mt][nt][3];
        *(bf16x4*)(&vs[col_l * 72 + k_l]) = o;
      }
    __syncthreads();
    const int col_l = t >> 2, seg = t & 3;
    const int b  = rbk >> 6;
    const int n0 = (rbk * 64) & 4095;
    bf16x8 v0 = *(const bf16x8*)(&vs[col_l * 72 + seg * 16]);
    bf16x8 v1 = *(const bf16x8*)(&vs[col_l * 72 + seg * 16 + 8]);
    __bf16* dst = Vt + (size_t)b * (256 * 4096) + (size_t)(ct * 64 + col_l) * 4096 + n0 + seg * 16;
    *(bf16x8*)(dst)     = v0;
    *(bf16x8*)(dst + 8) = v1;
  } else {
    float* dstb = (ct == 4) ? lbuf : rbuf;
#pragma unroll
    for (int mt = 0; mt < 2; ++mt)
#pragma unroll
      for (int nt = 0; nt < 2; ++nt) {
        const int col  = c0 + nt * 16 + l16;
        const int gr   = rbk * 64 + wr * 32 + mt * 16 + quad * 4;
#pragma unroll
        for (int rr = 0; rr < 4; ++rr)
          dstb[(size_t)(gr + rr) * 64 + col] = acc[mt][nt][rr];
      }
  }
}

// ---------------- fused attention GEMM, register-direct P, split-K
// grid (64, 8): x = 128-row band, y = K-split (512 k each, 8 chunks of 64).
// 4 waves = 4 row-waves x 1 col-wave; wave tile 32 rows x 256 cols (m=2 row-tiles).
__global__ __launch_bounds__(256, 2) void k_attn(const float* __restrict__ lbuf,
                                                 const float* __restrict__ rbuf,
                                                 const __bf16* __restrict__ Vt,
                                                 __bf16* __restrict__ part,
                                                 float* __restrict__ zpart) {
  __shared__ __align__(16) __bf16 vt[2][256 * 72];  // V chunk [col][k], stride 72 (2-way, free)
  const int t = threadIdx.x;
  const int lane = t & 63, w = t >> 6;
  const int l16 = lane & 15, quad = lane >> 4;
  const int rb = blockIdx.x;   // 0..63
  const int sp = blockIdx.y;   // 0..7
  const int g0 = rb * 128;
  const int bat = rb >> 5;
  const __bf16* Vb = Vt + (size_t)bat * (256 * 4096);
  const int row0 = g0 + w * 32;
  const int kbase = sp * 512;  // this split's k range within the batch

  // preload r fragments: rreg[mt][kk*8+j] = r[row][kk*32+quad*8+j]
  float rreg[2][16];
#pragma unroll
  for (int mt = 0; mt < 2; ++mt)
#pragma unroll
    for (int kk = 0; kk < 2; ++kk) {
      const float* rp = rbuf + (size_t)(row0 + mt * 16 + l16) * 64 + kk * 32 + quad * 8;
      f32x4 a = *(const f32x4*)(rp);
      f32x4 c = *(const f32x4*)(rp + 4);
#pragma unroll
      for (int j = 0; j < 4; ++j) { rreg[mt][kk * 8 + j] = a[j]; rreg[mt][kk * 8 + 4 + j] = c[j]; }
    }
  // preload l: lreg[mt][kc] = l[row][sp*8 + kc]
  float lreg[2][8];
#pragma unroll
  for (int mt = 0; mt < 2; ++mt) {
    const float* lp = lbuf + (size_t)(row0 + mt * 16 + l16) * 64 + sp * 8;
    f32x4 a = *(const f32x4*)(lp);
    f32x4 c = *(const f32x4*)(lp + 4);
#pragma unroll
    for (int j = 0; j < 4; ++j) { lreg[mt][j] = a[j]; lreg[mt][4 + j] = c[j]; }
  }

  f32x4 acc[2][16] = {};
  float zacc[2] = {0.f, 0.f};

  // stage chunk 0: unit p = it*256+t ; c = p>>3, o = p&7 (16 B each)
  {
    bf16x8 s0[4], s1[4];
#pragma unroll
    for (int it = 0; it < 4; ++it) {
      const int p = it * 256 + t;
      s0[it] = *(const bf16x8*)(Vb + (size_t)(p >> 3) * 4096 + kbase + (p & 7) * 8);
    }
#pragma unroll
    for (int it = 0; it < 4; ++it) {
      const int p = (it + 4) * 256 + t;
      s1[it] = *(const bf16x8*)(Vb + (size_t)(p >> 3) * 4096 + kbase + (p & 7) * 8);
    }
#pragma unroll
    for (int it = 0; it < 4; ++it) {
      const int p = it * 256 + t;
      *(bf16x8*)(&vt[0][(p >> 3) * 72 + (p & 7) * 8]) = s0[it];
    }
#pragma unroll
    for (int it = 0; it < 4; ++it) {
      const int p = (it + 4) * 256 + t;
      *(bf16x8*)(&vt[0][(p >> 3) * 72 + (p & 7) * 8]) = s1[it];
    }
  }
  __syncthreads();

#pragma unroll
  for (int kc = 0; kc < 8; ++kc) {
    const int cur = kc & 1;
    bf16x8 stg[4];
    // prefetch first half of next chunk
    if (kc < 7) {
      const int kn = kbase + (kc + 1) * 64;
#pragma unroll
      for (int it = 0; it < 4; ++it) {
        const int p = it * 256 + t;
        stg[it] = *(const bf16x8*)(Vb + (size_t)(p >> 3) * 4096 + kn + (p & 7) * 8);
      }
    }
    // generate A-fragments of P in registers
    bf16x8 af[2][2];
#pragma unroll
    for (int mt = 0; mt < 2; ++mt) {
      const float lv = lreg[mt][kc];
#pragma unroll
      for (int kk = 0; kk < 2; ++kk)
#pragma unroll
        for (int j = 0; j < 8; ++j) {
          const float e = __expf(lv * rreg[mt][kk * 8 + j]);
          zacc[mt] += e;
          af[mt][kk][j] = (__bf16)e;
        }
    }
    // write first half of next chunk, load second half
    bf16x8 stg2[4];
    if (kc < 7) {
      const int kn = kbase + (kc + 1) * 64;
#pragma unroll
      for (int it = 0; it < 4; ++it) {
        const int p = it * 256 + t;
        *(bf16x8*)(&vt[cur ^ 1][(p >> 3) * 72 + (p & 7) * 8]) = stg[it];
      }
#pragma unroll
      for (int it = 0; it < 4; ++it) {
        const int p = (it + 4) * 256 + t;
        stg2[it] = *(const bf16x8*)(Vb + (size_t)(p >> 3) * 4096 + kn + (p & 7) * 8);
      }
    }
    // MFMA over the current V chunk
    const __bf16* vb = vt[cur];
#pragma unroll
    for (int nt = 0; nt < 16; ++nt) {
      const __bf16* bp = vb + (nt * 16 + l16) * 72 + quad * 8;
      bf16x8 b0 = *(const bf16x8*)(bp);
      bf16x8 b1 = *(const bf16x8*)(bp + 32);
      acc[0][nt] = MFMA16(af[0][0], b0, acc[0][nt]);
      acc[0][nt] = MFMA16(af[0][1], b1, acc[0][nt]);
      acc[1][nt] = MFMA16(af[1][0], b0, acc[1][nt]);
      acc[1][nt] = MFMA16(af[1][1], b1, acc[1][nt]);
    }
    if (kc < 7) {
#pragma unroll
      for (int it = 0; it < 4; ++it) {
        const int p = (it + 4) * 256 + t;
        *(bf16x8*)(&vt[cur ^ 1][(p >> 3) * 72 + (p & 7) * 8]) = stg2[it];
      }
    }
    __syncthreads();
  }

  // Z partials: reduce across quads (cols), lanes 0..15 write
#pragma unroll
  for (int mt = 0; mt < 2; ++mt) {
    float z = zacc[mt];
    z += __shfl_xor(z, 16);
    z += __shfl_xor(z, 32);
    if (quad == 0) zpart[(size_t)sp * 8192 + row0 + mt * 16 + l16] = z;
  }
  // partial output (unnormalized, bf16): part[sp][row][col]
#pragma unroll
  for (int mt = 0; mt < 2; ++mt)
#pragma unroll
    for (int nt = 0; nt < 16; ++nt) {
      const int col = nt * 16 + l16;
      const int r0  = row0 + mt * 16 + quad * 4;
#pragma unroll
      for (int rr = 0; rr < 4; ++rr)
        part[(size_t)sp * (8192 * 256) + (size_t)(r0 + rr) * 256 + col] = (__bf16)acc[mt][nt][rr];
    }
}

// -------------- fixup: op = bf16( (sum_s part[s]) / Z ),  Z = sum_s zpart[s]
__global__ __launch_bounds__(256) void k_fix(const __bf16* __restrict__ part,
                                             const float* __restrict__ zpart,
                                             __bf16* __restrict__ op) {
  const int idx = blockIdx.x * 256 + threadIdx.x;  // 262144 threads, 8 elems each
  const int row = idx >> 5;
  const int c8  = (idx & 31) * 8;
  float z = 0.f;
#pragma unroll
  for (int s = 0; s < 8; ++s) z += zpart[(size_t)s * 8192 + row];
  const float iz = 1.0f / z;
  float sum[8] = {};
#pragma unroll
  for (int s = 0; s < 8; ++s) {
    bf16x8 p = *(const bf16x8*)(part + (size_t)s * (8192 * 256) + (size_t)row * 256 + c8);
#pragma unroll
    for (int j = 0; j < 8; ++j) sum[j] += (float)p[j];
  }
  bf16x8 o;
#pragma unroll
  for (int j = 0; j < 8; ++j) o[j] = (__bf16)(sum[j] * iz);
  *(bf16x8*)(op + (size_t)row * 256 + c8) = o;
}

// ----------------------------------------- out = op @ Wo (fp32), grid (128,4)
__global__ __launch_bounds__(256) void k_out(const __bf16* __restrict__ op,
                                             const __bf16* __restrict__ Wot,
                                             float* __restrict__ out) {
  const int t = threadIdx.x;
  const int lane = t & 63, wave = t >> 6;
  const int l16 = lane & 15, quad = lane >> 4;
  const int wr = wave >> 1, wc = wave & 1;
  const int rbk = blockIdx.x;
  const int ct  = blockIdx.y;
  const int row0 = rbk * 64 + wr * 32;
  const int c0   = ct * 64 + wc * 32;
  f32x4 acc[2][2] = {};
  for (int kk = 0; kk < 256; kk += 32) {
    const int ko = kk + quad * 8;
    bf16x8 a0 = *(const bf16x8*)(op + (size_t)(row0 + l16) * 256 + ko);
    bf16x8 a1 = *(const bf16x8*)(op + (size_t)(row0 + 16 + l16) * 256 + ko);
    bf16x8 b0 = *(const bf16x8*)(Wot + (size_t)(c0 + l16) * 256 + ko);
    bf16x8 b1 = *(const bf16x8*)(Wot + (size_t)(c0 + 16 + l16) * 256 + ko);
    acc[0][0] = MFMA16(a0, b0, acc[0][0]);
    acc[0][1] = MFMA16(a0, b1, acc[0][1]);
    acc[1][0] = MFMA16(a1, b0, acc[1][0]);
    acc[1][1] = MFMA16(a1, b1, acc[1][1]);
  }
#pragma unroll
  for (int mt = 0; mt < 2; ++mt)
#pragma unroll
    for (int nt = 0; nt < 2; ++nt) {
      const int col = c0 + nt * 16 + l16;
      const int r0  = row0 + mt * 16 + quad * 4;
#pragma unroll
      for (int rr = 0; rr < 4; ++rr)
        out[(size_t)(r0 + rr) * 256 + col] = acc[mt][nt][rr];
    }
}

extern "C" void kernel_launch(void* const* d_in, const int* in_sizes, int n_in,
                              void* d_out, int out_size, void* d_ws, size_t ws_size,
                              hipStream_t stream) {
  const float* x  = (const float*)d_in[0];
  const float* Wl = (const float*)d_in[1];
  const float* Wr = (const float*)d_in[2];
  const float* Wv = (const float*)d_in[3];
  const float* Wo = (const float*)d_in[4];
  char* ws = (char*)d_ws;
  __bf16* xb   = (__bf16*)(ws + OFF_XB);
  __bf16* Wvt  = (__bf16*)(ws + OFF_WVT);
  __bf16* Wlt  = (__bf16*)(ws + OFF_WLT);
  __bf16* Wrt  = (__bf16*)(ws + OFF_WRT);
  __bf16* Wot  = (__bf16*)(ws + OFF_WOT);
  __bf16* Vt   = (__bf16*)(ws + OFF_VT);
  float*  lb   = (float*)(ws + OFF_L);
  float*  rbf  = (float*)(ws + OFF_R);
  __bf16* op   = (__bf16*)(ws + OFF_OP);
  __bf16* prt  = (__bf16*)(ws + OFF_PART);
  float*  zp   = (float*)(ws + OFF_ZP);
  float*  out  = (float*)d_out;

  k_prep<<<2688, 256, 0, stream>>>(x, Wv, Wl, Wr, Wo, xb, Wvt, Wlt, Wrt, Wot);
  k_proj<<<dim3(128, 6), 256, 0, stream>>>(xb, Wvt, Wlt, Wrt, Vt, lb, rbf);
  k_attn<<<dim3(64, 8), 256, 0, stream>>>(lb, rbf, Vt, prt, zp);
  k_fix<<<1024, 256, 0, stream>>>(prt, zp, op);
  k_out<<<dim3(128, 4), 256, 0, stream>>>(op, Wot, out);
}

// Round 3
// 145.186 us; speedup vs baseline: 1.3245x; 1.0480x over previous
//
#include <hip/hip_runtime.h>
#include <hip/hip_bf16.h>

typedef __attribute__((ext_vector_type(8))) __bf16 bf16x8;
typedef __attribute__((ext_vector_type(4))) __bf16 bf16x4;
typedef __attribute__((ext_vector_type(4))) float  f32x4;

#define MFMA16(a, b, c) __builtin_amdgcn_mfma_f32_16x16x32_bf16((a), (b), (c), 0, 0, 0)

// B=2, S=4096, D=256, P=R=64. Flattened rows g = b*4096 + n (8192 total).
static constexpr size_t OFF_XB   = 0;                        // bf16 [8192][256]   4 MiB
static constexpr size_t OFF_WVT  = 4u << 20;                 // bf16 [256][256] ([n][k])
static constexpr size_t OFF_WLT  = OFF_WVT + 256 * 256 * 2;  // bf16 [64][256]
static constexpr size_t OFF_WRT  = OFF_WLT + 64 * 256 * 2;   // bf16 [64][256]
static constexpr size_t OFF_WOT  = OFF_WRT + 64 * 256 * 2;   // bf16 [256][256]
static constexpr size_t OFF_VT   = 5u << 20;                 // bf16 [2][64][8][256][8] packed V 4 MiB
static constexpr size_t OFF_L    = 9u << 20;                 // f32  [8192][64]    2 MiB
static constexpr size_t OFF_R    = 11u << 20;                // f32  [8192][64]    2 MiB
static constexpr size_t OFF_OP   = 13u << 20;                // bf16 [8192][256]   4 MiB
static constexpr size_t OFF_PART = 17u << 20;                // bf16 [8][8192][256] 32 MiB
static constexpr size_t OFF_ZP   = 49u << 20;                // f32  [8][8192]     256 KiB

__device__ __forceinline__ void load_lds16(const __bf16* g, __bf16* l) {
  __builtin_amdgcn_global_load_lds((__attribute__((address_space(1))) void*)g,
                                   (__attribute__((address_space(3))) void*)l, 16, 0, 0);
}

// ------------------------------------------- x -> bf16  +  weight transpose
__global__ __launch_bounds__(256) void k_prep(const float* __restrict__ x,
                                              const float* __restrict__ Wv,
                                              const float* __restrict__ Wl,
                                              const float* __restrict__ Wr,
                                              const float* __restrict__ Wo,
                                              __bf16* __restrict__ xb,
                                              __bf16* __restrict__ Wvt,
                                              __bf16* __restrict__ Wlt,
                                              __bf16* __restrict__ Wrt,
                                              __bf16* __restrict__ Wot) {
  const int bx = blockIdx.x, t = threadIdx.x;
  if (bx < 2048) {
    const int i = (bx * 256 + t) * 4;
    const float4 v = *(const float4*)(x + i);
    bf16x4 o;
    o.x = (__bf16)v.x; o.y = (__bf16)v.y; o.z = (__bf16)v.z; o.w = (__bf16)v.w;
    *(bf16x4*)(xb + i) = o;
    return;
  }
  const int idx = (bx - 2048) * 256 + t;
  if (idx < 65536) {
    const int k = idx >> 8, n = idx & 255;
    Wvt[n * 256 + k] = (__bf16)Wv[idx];
  } else if (idx < 81920) {
    const int j = idx - 65536;
    const int k = j >> 6, n = j & 63;
    Wlt[n * 256 + k] = (__bf16)Wl[j];
  } else if (idx < 98304) {
    const int j = idx - 81920;
    const int k = j >> 6, n = j & 63;
    Wrt[n * 256 + k] = (__bf16)Wr[j];
  } else {
    const int j = idx - 98304;
    const int k = j >> 8, n = j & 255;
    Wot[n * 256 + k] = (__bf16)Wo[j];
  }
}

// --------- projections: V packed [bat][mc][m8][d][j] (bf16), l, r (fp32)
// grid (128, 6): x = 64-row block; y: 0..3 Wv d-tiles, 4 -> Wl, 5 -> Wr
__global__ __launch_bounds__(256) void k_proj(const __bf16* __restrict__ xb,
                                              const __bf16* __restrict__ Wvt,
                                              const __bf16* __restrict__ Wlt,
                                              const __bf16* __restrict__ Wrt,
                                              __bf16* __restrict__ Vt,
                                              float* __restrict__ lbuf,
                                              float* __restrict__ rbuf) {
  __shared__ __align__(16) __bf16 vs[8 * 64 * 8];  // [m8][d_local][j]
  const int t = threadIdx.x;
  const int lane = t & 63, wave = t >> 6;
  const int l16 = lane & 15, quad = lane >> 4;
  const int wr = wave >> 1, wc = wave & 1;
  const int rbk = blockIdx.x;
  const int ct  = blockIdx.y;
  const __bf16* Wt;
  int colbase;
  if (ct < 4)       { Wt = Wvt; colbase = ct * 64; }
  else if (ct == 4) { Wt = Wlt; colbase = 0; }
  else              { Wt = Wrt; colbase = 0; }
  const int row0 = rbk * 64 + wr * 32;
  const int c0   = colbase + wc * 32;
  f32x4 acc[2][2] = {};
  for (int kk = 0; kk < 256; kk += 32) {
    const int ko = kk + quad * 8;
    bf16x8 a0 = *(const bf16x8*)(xb + (size_t)(row0 + l16) * 256 + ko);
    bf16x8 a1 = *(const bf16x8*)(xb + (size_t)(row0 + 16 + l16) * 256 + ko);
    bf16x8 b0 = *(const bf16x8*)(Wt + (size_t)(c0 + l16) * 256 + ko);
    bf16x8 b1 = *(const bf16x8*)(Wt + (size_t)(c0 + 16 + l16) * 256 + ko);
    acc[0][0] = MFMA16(a0, b0, acc[0][0]);
    acc[0][1] = MFMA16(a0, b1, acc[0][1]);
    acc[1][0] = MFMA16(a1, b0, acc[1][0]);
    acc[1][1] = MFMA16(a1, b1, acc[1][1]);
  }
  if (ct < 4) {
    // D row r_local = wr*32+mt*16+quad*4+rr, col d_local = wc*32+nt*16+l16
    // vs[m8][d][j]: m8 = r_local>>3 (const over rr), j = (quad&1)*4 + rr
#pragma unroll
    for (int mt = 0; mt < 2; ++mt)
#pragma unroll
      for (int nt = 0; nt < 2; ++nt) {
        const int m8 = wr * 4 + mt * 2 + (quad >> 1);
        const int d  = wc * 32 + nt * 16 + l16;
        bf16x4 o;
        o.x = (__bf16)acc[mt][nt][0];
        o.y = (__bf16)acc[mt][nt][1];
        o.z = (__bf16)acc[mt][nt][2];
        o.w = (__bf16)acc[mt][nt][3];
        *(bf16x4*)(&vs[m8 * 512 + d * 8 + (quad & 1) * 4]) = o;
      }
    __syncthreads();
    const int m8 = t >> 5, s32 = t & 31;
    const int bat = rbk >> 6, mc = rbk & 63;
    bf16x8 a = *(const bf16x8*)(&vs[m8 * 512 + s32 * 16]);
    bf16x8 b = *(const bf16x8*)(&vs[m8 * 512 + s32 * 16 + 8]);
    __bf16* dst = Vt + (size_t)bat * 1048576 + (size_t)mc * 16384 +
                  m8 * 2048 + ct * 512 + s32 * 16;
    *(bf16x8*)dst       = a;
    *(bf16x8*)(dst + 8) = b;
  } else {
    float* dstb = (ct == 4) ? lbuf : rbuf;
#pragma unroll
    for (int mt = 0; mt < 2; ++mt)
#pragma unroll
      for (int nt = 0; nt < 2; ++nt) {
        const int col = c0 + nt * 16 + l16;
        const int gr  = rbk * 64 + wr * 32 + mt * 16 + quad * 4;
#pragma unroll
        for (int rr = 0; rr < 4; ++rr)
          dstb[(size_t)(gr + rr) * 64 + col] = acc[mt][nt][rr];
      }
  }
}

// ---------------- fused attention GEMM: register P-gen, split-K=8, DMA staging
// grid (64, 8). 4 waves: 2 row-waves (64 rows) x 2 col-waves (128 cols).
__global__ __launch_bounds__(256, 2) void k_attn(const float* __restrict__ lbuf,
                                                 const float* __restrict__ rbuf,
                                                 const __bf16* __restrict__ Vt,
                                                 __bf16* __restrict__ part,
                                                 float* __restrict__ zpart) {
  __shared__ __align__(16) char smem[70144];  // vt0 32K | vt1 32K | ls 4.6K ; epi reuses 66.6K
  __bf16* vt0 = (__bf16*)smem;
  __bf16* vt1 = (__bf16*)(smem + 32768);
  float*  ls  = (float*)(smem + 65536);       // [128][9] l-tile, pad 9
  const int t = threadIdx.x;
  const int lane = t & 63, w = t >> 6;
  const int l16 = lane & 15, quad = lane >> 4;
  const int wr = w >> 1, wc = w & 1;
  const int rb = blockIdx.x;   // 0..63
  const int sp = blockIdx.y;   // 0..7
  const int g0 = rb * 128;
  const int bat = rb >> 5;
  const int row0 = g0 + wr * 64;
  const __bf16* Vbase = Vt + (size_t)bat * 1048576;

  // l tile: rows g0..+127, cols sp*8..+8 (pre-pad stride 9)
  {
    const int rl = t >> 1, half = t & 1;
    f32x4 v = *(const f32x4*)(lbuf + (size_t)(g0 + rl) * 64 + sp * 8 + half * 4);
#pragma unroll
    for (int i = 0; i < 4; ++i) ls[rl * 9 + half * 4 + i] = v[i];
  }
  // r frags, pre-scaled by log2(e): rreg[mt][kk*8+j] = r[row][kk*32+quad*8+j]*LOG2E
  const float LOG2E = 1.44269504088896f;
  float rreg[4][16];
#pragma unroll
  for (int mt = 0; mt < 4; ++mt) {
    const float* rp = rbuf + (size_t)(row0 + mt * 16 + l16) * 64;
#pragma unroll
    for (int kk = 0; kk < 2; ++kk) {
      f32x4 a = *(const f32x4*)(rp + kk * 32 + quad * 8);
      f32x4 b = *(const f32x4*)(rp + kk * 32 + quad * 8 + 4);
#pragma unroll
      for (int j = 0; j < 4; ++j) {
        rreg[mt][kk * 8 + j]     = a[j] * LOG2E;
        rreg[mt][kk * 8 + 4 + j] = b[j] * LOG2E;
      }
    }
  }

  f32x4 acc[4][8] = {};
  float zacc[4] = {0.f, 0.f, 0.f, 0.f};

  // stage chunk sp*8 into vt0 (8 DMA ops per wave, lane-linear)
  {
    const __bf16* g = Vbase + (size_t)(sp * 8) * 16384;
#pragma unroll
    for (int i = 0; i < 8; ++i)
      load_lds16(g + (size_t)(i * 256 + w * 64 + lane) * 8, vt0 + (i * 256 + w * 64) * 8);
  }
  __syncthreads();

  for (int kc = 0; kc < 8; ++kc) {
    __bf16* cur = (kc & 1) ? vt1 : vt0;
    __bf16* nxt = (kc & 1) ? vt0 : vt1;
    if (kc < 7) {
      const __bf16* g = Vbase + (size_t)(sp * 8 + kc + 1) * 16384;
#pragma unroll
      for (int i = 0; i < 8; ++i)
        load_lds16(g + (size_t)(i * 256 + w * 64 + lane) * 8, nxt + (i * 256 + w * 64) * 8);
    }
    float lv[4];
#pragma unroll
    for (int mt = 0; mt < 4; ++mt) lv[mt] = ls[(wr * 64 + mt * 16 + l16) * 9 + kc];
#pragma unroll
    for (int kk = 0; kk < 2; ++kk) {
      bf16x8 af[4];
#pragma unroll
      for (int mt = 0; mt < 4; ++mt) {
#pragma unroll
        for (int j = 0; j < 8; ++j) {
          const float e = exp2f(lv[mt] * rreg[mt][kk * 8 + j]);
          zacc[mt] += e;
          af[mt][j] = (__bf16)e;
        }
      }
#pragma unroll
      for (int nt = 0; nt < 8; ++nt) {
        bf16x8 bv = *(const bf16x8*)(cur + (kk * 4 + quad) * 2048 +
                                     (wc * 128 + nt * 16 + l16) * 8);
        acc[0][nt] = MFMA16(af[0], bv, acc[0][nt]);
        acc[1][nt] = MFMA16(af[1], bv, acc[1][nt]);
        acc[2][nt] = MFMA16(af[2], bv, acc[2][nt]);
        acc[3][nt] = MFMA16(af[3], bv, acc[3][nt]);
      }
    }
    __syncthreads();
  }

  // Z partials: reduce over quads
#pragma unroll
  for (int mt = 0; mt < 4; ++mt) {
    float z = zacc[mt];
    z += __shfl_xor(z, 16);
    z += __shfl_xor(z, 32);
    if (wc == 0 && quad == 0)
      zpart[(size_t)sp * 8192 + row0 + mt * 16 + l16] = z;
  }

  // epilogue: stage C tile to LDS (stride 260), then coalesced bf16x8 writes
  __bf16* ctile = (__bf16*)smem;
#pragma unroll
  for (int mt = 0; mt < 4; ++mt)
#pragma unroll
    for (int nt = 0; nt < 8; ++nt) {
      const int r0 = wr * 64 + mt * 16 + quad * 4;
      const int c  = wc * 128 + nt * 16 + l16;
#pragma unroll
      for (int rr = 0; rr < 4; ++rr)
        ctile[(r0 + rr) * 260 + c] = (__bf16)acc[mt][nt][rr];
    }
  __syncthreads();
#pragma unroll
  for (int p = 0; p < 16; ++p) {
    const int idx = p * 256 + t;
    const int row = idx >> 5, seg = idx & 31;
    bf16x8 v = *(const bf16x8*)(ctile + row * 260 + seg * 8);
    *(bf16x8*)(part + (size_t)sp * (8192 * 256) + (size_t)(g0 + row) * 256 + seg * 8) = v;
  }
}

// -------------- fixup: op = bf16( (sum_s part[s]) / Z ),  Z = sum_s zpart[s]
__global__ __launch_bounds__(256) void k_fix(const __bf16* __restrict__ part,
                                             const float* __restrict__ zpart,
                                             __bf16* __restrict__ op) {
  const int idx = blockIdx.x * 256 + threadIdx.x;
  const int row = idx >> 5;
  const int c8  = (idx & 31) * 8;
  float z = 0.f;
#pragma unroll
  for (int s = 0; s < 8; ++s) z += zpart[(size_t)s * 8192 + row];
  const float iz = 1.0f / z;
  float sum[8] = {};
#pragma unroll
  for (int s = 0; s < 8; ++s) {
    bf16x8 p = *(const bf16x8*)(part + (size_t)s * (8192 * 256) + (size_t)row * 256 + c8);
#pragma unroll
    for (int j = 0; j < 8; ++j) sum[j] += (float)p[j];
  }
  bf16x8 o;
#pragma unroll
  for (int j = 0; j < 8; ++j) o[j] = (__bf16)(sum[j] * iz);
  *(bf16x8*)(op + (size_t)row * 256 + c8) = o;
}

// ----------------------------------------- out = op @ Wo (fp32), grid (128,4)
__global__ __launch_bounds__(256) void k_out(const __bf16* __restrict__ op,
                                             const __bf16* __restrict__ Wot,
                                             float* __restrict__ out) {
  const int t = threadIdx.x;
  const int lane = t & 63, wave = t >> 6;
  const int l16 = lane & 15, quad = lane >> 4;
  const int wr = wave >> 1, wc = wave & 1;
  const int rbk = blockIdx.x;
  const int ct  = blockIdx.y;
  const int row0 = rbk * 64 + wr * 32;
  const int c0   = ct * 64 + wc * 32;
  f32x4 acc[2][2] = {};
  for (int kk = 0; kk < 256; kk += 32) {
    const int ko = kk + quad * 8;
    bf16x8 a0 = *(const bf16x8*)(op + (size_t)(row0 + l16) * 256 + ko);
    bf16x8 a1 = *(const bf16x8*)(op + (size_t)(row0 + 16 + l16) * 256 + ko);
    bf16x8 b0 = *(const bf16x8*)(Wot + (size_t)(c0 + l16) * 256 + ko);
    bf16x8 b1 = *(const bf16x8*)(Wot + (size_t)(c0 + 16 + l16) * 256 + ko);
    acc[0][0] = MFMA16(a0, b0, acc[0][0]);
    acc[0][1] = MFMA16(a0, b1, acc[0][1]);
    acc[1][0] = MFMA16(a1, b0, acc[1][0]);
    acc[1][1] = MFMA16(a1, b1, acc[1][1]);
  }
#pragma unroll
  for (int mt = 0; mt < 2; ++mt)
#pragma unroll
    for (int nt = 0; nt < 2; ++nt) {
      const int col = c0 + nt * 16 + l16;
      const int r0  = row0 + mt * 16 + quad * 4;
#pragma unroll
      for (int rr = 0; rr < 4; ++rr)
        out[(size_t)(r0 + rr) * 256 + col] = acc[mt][nt][rr];
    }
}

extern "C" void kernel_launch(void* const* d_in, const int* in_sizes, int n_in,
                              void* d_out, int out_size, void* d_ws, size_t ws_size,
                              hipStream_t stream) {
  const float* x  = (const float*)d_in[0];
  const float* Wl = (const float*)d_in[1];
  const float* Wr = (const float*)d_in[2];
  const float* Wv = (const float*)d_in[3];
  const float* Wo = (const float*)d_in[4];
  char* ws = (char*)d_ws;
  __bf16* xb   = (__bf16*)(ws + OFF_XB);
  __bf16* Wvt  = (__bf16*)(ws + OFF_WVT);
  __bf16* Wlt  = (__bf16*)(ws + OFF_WLT);
  __bf16* Wrt  = (__bf16*)(ws + OFF_WRT);
  __bf16* Wot  = (__bf16*)(ws + OFF_WOT);
  __bf16* Vt   = (__bf16*)(ws + OFF_VT);
  float*  lb   = (float*)(ws + OFF_L);
  float*  rbf  = (float*)(ws + OFF_R);
  __bf16* op   = (__bf16*)(ws + OFF_OP);
  __bf16* prt  = (__bf16*)(ws + OFF_PART);
  float*  zp   = (float*)(ws + OFF_ZP);
  float*  out  = (float*)d_out;

  k_prep<<<2688, 256, 0, stream>>>(x, Wv, Wl, Wr, Wo, xb, Wvt, Wlt, Wrt, Wot);
  k_proj<<<dim3(128, 6), 256, 0, stream>>>(xb, Wvt, Wlt, Wrt, Vt, lb, rbf);
  k_attn<<<dim3(64, 8), 256, 0, stream>>>(lb, rbf, Vt, prt, zp);
  k_fix<<<1024, 256, 0, stream>>>(prt, zp, op);
  k_out<<<dim3(128, 4), 256, 0, stream>>>(op, Wot, out);
}